// Round 3
// baseline (1904.642 us; speedup 1.0000x reference)
//
#include <hip/hip_runtime.h>

typedef __bf16 bf16x8 __attribute__((ext_vector_type(8)));
typedef float f32x4 __attribute__((ext_vector_type(4)));

constexpr int cN   = 20000;   // nodes total
constexpr int cG   = 200;     // graphs
constexpr int cNPG = 100;     // nodes per graph
constexpr int cE   = 160000;  // edges total
constexpr int cEPG = 800;     // edges per graph
constexpr int cHID = 256;
constexpr int cIN  = 21;
constexpr float cEPS   = 1e-5f;
constexpr float cSLOPE = 0.2f;

// ---- monotone float<->uint encoding for atomicMax-based segment max ----
__device__ __forceinline__ unsigned enc_f(float f) {
    unsigned u = __float_as_uint(f);
    return (u & 0x80000000u) ? ~u : (u | 0x80000000u);
}
__device__ __forceinline__ float dec_f(unsigned u) {
    u = (u & 0x80000000u) ? (u & 0x7fffffffu) : ~u;
    return __uint_as_float(u);
}

// ---- layer-0: fs = x@Ws+bs, fd = x@Wd+bd, res = x@Wres  (K=21, f32 exact) ----
__global__ __launch_bounds__(256) void k_in_gemm(
    const float* __restrict__ x,
    const float* __restrict__ Ws, const float* __restrict__ bs,
    const float* __restrict__ Wd, const float* __restrict__ bd,
    const float* __restrict__ Wr,
    float* __restrict__ fs, float* __restrict__ fd, float* __restrict__ res)
{
    __shared__ float xl[8 * cIN];
    int tid = threadIdx.x;
    int rb  = blockIdx.x * 8;
    if (tid < 8 * cIN) xl[tid] = x[(size_t)rb * cIN + tid];
    __syncthreads();
    int j = tid;
    float ws[cIN], wd[cIN], wr[cIN];
#pragma unroll
    for (int k = 0; k < cIN; ++k) {
        ws[k] = Ws[k * cHID + j];
        wd[k] = Wd[k * cHID + j];
        wr[k] = Wr[k * cHID + j];
    }
    float vbs = bs[j], vbd = bd[j];
    for (int r = 0; r < 8; ++r) {
        float as = vbs, ad = vbd, ar = 0.f;
#pragma unroll
        for (int k = 0; k < cIN; ++k) {
            float xv = xl[r * cIN + k];
            as += xv * ws[k];
            ad += xv * wd[k];
            ar += xv * wr[k];
        }
        size_t o = (size_t)(rb + r) * cHID + j;
        fs[o] = as; fd[o] = ad; res[o] = ar;
    }
}

// ---- weight convert + transpose: WT[n][k] = bf16(W[k][n]) ----
__global__ __launch_bounds__(256) void k_wcvt(
    const float* __restrict__ W, __bf16* __restrict__ WT)
{
    int k = blockIdx.x, n = threadIdx.x;
    WT[(size_t)n * cHID + k] = (__bf16)W[(size_t)k * cHID + n];
}

// ---- layers 1-3: fs = h@Ws+bs, fd = h@Wd+bd via bf16 MFMA, f32 accum ----
// A frag: lane holds A[lane&15][ (lane>>4)*8 + i ]  (row-major h, contiguous k)
// B frag: lane holds B[ (lane>>4)*8 + i ][lane&15]  (read from W^T, contiguous k)
// D:      lane holds D[(lane>>4)*4 + i][lane&15]
__global__ __launch_bounds__(256) void k_gemm_mfma(
    const __bf16* __restrict__ hb,
    const __bf16* __restrict__ WsT, const __bf16* __restrict__ WdT,
    const float* __restrict__ bs, const float* __restrict__ bd,
    float* __restrict__ fs, float* __restrict__ fd)
{
    int wave  = threadIdx.x >> 6;
    int lane  = threadIdx.x & 63;
    int strip = blockIdx.x * 4 + wave;        // 16-row strip
    if (strip >= cN / 16) return;
    int n0 = blockIdx.y * 64;                 // 64-col tile
    int rc = lane & 15;
    int kg = lane >> 4;
    int m0 = strip * 16;

    f32x4 accS[4], accD[4];
#pragma unroll
    for (int c = 0; c < 4; ++c) {
        accS[c] = (f32x4){0.f, 0.f, 0.f, 0.f};
        accD[c] = (f32x4){0.f, 0.f, 0.f, 0.f};
    }

    const __bf16* ap  = hb  + (size_t)(m0 + rc) * cHID + kg * 8;
    const __bf16* bsp = WsT + (size_t)(n0 + rc) * cHID + kg * 8;
    const __bf16* bdp = WdT + (size_t)(n0 + rc) * cHID + kg * 8;

#pragma unroll 2
    for (int k0 = 0; k0 < cHID; k0 += 32) {
        bf16x8 a = *(const bf16x8*)(ap + k0);
#pragma unroll
        for (int c = 0; c < 4; ++c) {
            bf16x8 bS = *(const bf16x8*)(bsp + (size_t)c * 16 * cHID + k0);
            bf16x8 bD = *(const bf16x8*)(bdp + (size_t)c * 16 * cHID + k0);
            accS[c] = __builtin_amdgcn_mfma_f32_16x16x32_bf16(a, bS, accS[c], 0, 0, 0);
            accD[c] = __builtin_amdgcn_mfma_f32_16x16x32_bf16(a, bD, accD[c], 0, 0, 0);
        }
    }
#pragma unroll
    for (int c = 0; c < 4; ++c) {
        int col = n0 + c * 16 + rc;
        float vbs = bs[col], vbd = bd[col];
#pragma unroll
        for (int i = 0; i < 4; ++i) {
            size_t o = (size_t)(m0 + kg * 4 + i) * cHID + col;
            fs[o] = accS[c][i] + vbs;
            fd[o] = accD[c][i] + vbd;
        }
    }
}

// ---- per-(graph, 128-dim half) edge stage: score -> softmax -> scatter-sum ----
__global__ __launch_bounds__(256) void k_edge(
    const float* __restrict__ fs, const float* __restrict__ fd,
    const float* __restrict__ res, const float* __restrict__ avec,
    const int* __restrict__ src, const int* __restrict__ dst,
    float* __restrict__ hpre, float* __restrict__ attn_out)
{
    __shared__ float    rst[cNPG * 128];
    __shared__ float    sco[cEPG];
    __shared__ unsigned menc[cNPG];
    __shared__ float    den[cNPG];

    int g    = blockIdx.x;
    int half = blockIdx.y;                // 0 or 1: which 128 dims we aggregate
    int tid  = threadIdx.x;
    int lane = tid & 63, wave = tid >> 6;
    int nb = g * cNPG, eb = g * cEPG;
    int dbase = half * 128;

    for (int i = tid; i < cNPG * 128; i += 256) rst[i] = 0.f;
    if (tid < cNPG) { menc[tid] = 0u; den[tid] = 0.f; }
    __syncthreads();

    // ---- scores: wave per edge, stride-64 dims per lane ----
    float a0 = avec[lane], a1 = avec[lane + 64], a2 = avec[lane + 128], a3 = avec[lane + 192];
    for (int el = wave; el < cEPG; el += 4) {
        int e = eb + el;
        int s = src[e], d = dst[e];
        const float* fsp = fs + (size_t)s * cHID;
        const float* fdp = fd + (size_t)d * cHID;
        float v0 = fsp[lane]       + fdp[lane];
        float v1 = fsp[lane + 64]  + fdp[lane + 64];
        float v2 = fsp[lane + 128] + fdp[lane + 128];
        float v3 = fsp[lane + 192] + fdp[lane + 192];
        v0 = v0 > 0.f ? v0 : cSLOPE * v0;
        v1 = v1 > 0.f ? v1 : cSLOPE * v1;
        v2 = v2 > 0.f ? v2 : cSLOPE * v2;
        v3 = v3 > 0.f ? v3 : cSLOPE * v3;
        float part = v0 * a0 + v1 * a1 + v2 * a2 + v3 * a3;
#pragma unroll
        for (int off = 32; off > 0; off >>= 1) part += __shfl_xor(part, off);
        if (lane == 0) {
            sco[el] = part;
            atomicMax(&menc[d - nb], enc_f(part));
        }
    }
    __syncthreads();

    // ---- ex = exp(s - m), denominator ----
    for (int el = tid; el < cEPG; el += 256) {
        int d = dst[eb + el] - nb;
        float ex = __expf(sco[el] - dec_f(menc[d]));
        sco[el] = ex;
        atomicAdd(&den[d], ex);
    }
    __syncthreads();

    // ---- alpha; write attns (half 0 only) ----
    for (int el = tid; el < cEPG; el += 256) {
        int d = dst[eb + el] - nb;
        float alpha = sco[el] / den[d];
        sco[el] = alpha;
        if (half == 0) attn_out[(size_t)(eb + el) * 4] = alpha;
    }
    __syncthreads();

    // ---- rst[dst] += alpha * fs[src]  (this block's 128 dims) ----
    for (int el = wave; el < cEPG; el += 4) {
        int e = eb + el;
        int s = src[e], dl = dst[e] - nb;
        float alpha = sco[el];
        const float* fsp = fs + (size_t)s * cHID + dbase;
        atomicAdd(&rst[dl * 128 + lane],      alpha * fsp[lane]);
        atomicAdd(&rst[dl * 128 + lane + 64], alpha * fsp[lane + 64]);
    }
    __syncthreads();

    // ---- hpre = rst + res ----
    for (int i = tid; i < cNPG * 128; i += 256) {
        int nl = i >> 7, dd = i & 127;
        size_t gi = (size_t)(nb + nl) * cHID + dbase + dd;
        hpre[gi] = rst[i] + res[gi];
    }
}

// ---- BN stats: column sums / sumsq over all 20000 rows ----
__global__ __launch_bounds__(256) void k_bn_stats(
    const float* __restrict__ hpre, float* __restrict__ gsum, float* __restrict__ gssq)
{
    int j = threadIdx.x;
    int rb = blockIdx.x * cNPG;
    float s = 0.f, q = 0.f;
    for (int r = 0; r < cNPG; ++r) {
        float v = hpre[(size_t)(rb + r) * cHID + j];
        s += v; q += v * v;
    }
    atomicAdd(&gsum[j], s);
    atomicAdd(&gssq[j], q);
}

// ---- BN apply + ReLU + graph mean; emit f32 h and bf16 h ----
__global__ __launch_bounds__(256) void k_bn_apply(
    const float* __restrict__ hpre,
    const float* __restrict__ gsum, const float* __restrict__ gssq,
    const float* __restrict__ gamma, const float* __restrict__ beta,
    float* __restrict__ h, __bf16* __restrict__ hb, float* __restrict__ featcat)
{
    int j = threadIdx.x, g = blockIdx.x;
    float mu  = gsum[j] * (1.f / cN);
    float var = gssq[j] * (1.f / cN) - mu * mu;
    float sc  = gamma[j] * rsqrtf(var + cEPS);
    float sh  = beta[j] - mu * sc;
    float fsum = 0.f;
    for (int r = 0; r < cNPG; ++r) {
        size_t i = (size_t)(g * cNPG + r) * cHID + j;
        float v = hpre[i] * sc + sh;
        v = v > 0.f ? v : 0.f;
        h[i] = v;
        hb[i] = (__bf16)v;
        fsum += v;
    }
    featcat[(size_t)g * (4 * cHID) + j] = fsum * (1.f / cNPG);
}

// ---- head: feat2 = featcat @ fc1_W + fc1_b ----
__global__ __launch_bounds__(256) void k_fc1(
    const float* __restrict__ featcat, const float* __restrict__ W,
    const float* __restrict__ b, float* __restrict__ out)
{
    __shared__ float row[4 * cHID];
    int g = blockIdx.x, j = threadIdx.x;
    for (int i = j; i < 4 * cHID; i += 256) row[i] = featcat[(size_t)g * (4 * cHID) + i];
    __syncthreads();
    float acc = b[j];
    for (int k = 0; k < 4 * cHID; ++k) acc += row[k] * W[(size_t)k * cHID + j];
    out[(size_t)g * cHID + j] = acc;
}

// ---- head BN (over 200 rows) + ReLU, in place ----
__global__ __launch_bounds__(256) void k_fc_bn(
    float* __restrict__ f2, const float* __restrict__ gamma, const float* __restrict__ beta)
{
    int j = threadIdx.x;
    float s = 0.f, q = 0.f;
    for (int r = 0; r < cG; ++r) { float v = f2[(size_t)r * cHID + j]; s += v; q += v * v; }
    float mu  = s * (1.f / cG);
    float var = q * (1.f / cG) - mu * mu;
    float sc  = gamma[j] * rsqrtf(var + cEPS);
    float sh  = beta[j] - mu * sc;
    for (int r = 0; r < cG; ++r) {
        float v = f2[(size_t)r * cHID + j] * sc + sh;
        f2[(size_t)r * cHID + j] = v > 0.f ? v : 0.f;
    }
}

// ---- head: out[r*5+o] = feat2[r] . fc2_W[:,o] + fc2_b[o] ----
__global__ __launch_bounds__(256) void k_fc2(
    const float* __restrict__ f2, const float* __restrict__ W,
    const float* __restrict__ b, float* __restrict__ out)
{
    int t = blockIdx.x * 256 + threadIdx.x;
    if (t >= cG * 5) return;
    int r = t / 5, o = t % 5;
    float acc = b[o];
    for (int k = 0; k < cHID; ++k) acc += f2[(size_t)r * cHID + k] * W[k * 5 + o];
    out[t] = acc;
}

extern "C" void kernel_launch(void* const* d_in, const int* in_sizes, int n_in,
                              void* d_out, int out_size, void* d_ws, size_t ws_size,
                              hipStream_t stream)
{
    (void)in_sizes; (void)n_in; (void)out_size; (void)ws_size;
    const float* x     = (const float*)d_in[0];
    const float* Ws0   = (const float*)d_in[1];
    const float* bs0   = (const float*)d_in[2];
    const float* Wd0   = (const float*)d_in[3];
    const float* bd0   = (const float*)d_in[4];
    const float* a0    = (const float*)d_in[5];
    const float* Wres0 = (const float*)d_in[6];
    const float* g0    = (const float*)d_in[7];
    const float* be0   = (const float*)d_in[8];
    const float* Ws_r  = (const float*)d_in[9];
    const float* bs_r  = (const float*)d_in[10];
    const float* Wd_r  = (const float*)d_in[11];
    const float* bd_r  = (const float*)d_in[12];
    const float* a_r   = (const float*)d_in[13];
    const float* g_r   = (const float*)d_in[14];
    const float* be_r  = (const float*)d_in[15];
    const float* fc1_W = (const float*)d_in[16];
    const float* fc1_b = (const float*)d_in[17];
    const float* gfc   = (const float*)d_in[18];
    const float* bfc   = (const float*)d_in[19];
    const float* fc2_W = (const float*)d_in[20];
    const float* fc2_b = (const float*)d_in[21];
    const int*   src   = (const int*)d_in[22];
    const int*   dst   = (const int*)d_in[23];
    float* out = (float*)d_out;

    char* p = (char*)d_ws;
    float* h       = (float*)p; p += (size_t)cN * cHID * 4;
    float* fs      = (float*)p; p += (size_t)cN * cHID * 4;
    float* fd      = (float*)p; p += (size_t)cN * cHID * 4;
    float* hpre    = (float*)p; p += (size_t)cN * cHID * 4;
    float* featcat = (float*)p; p += (size_t)cG * 4 * cHID * 4;
    float* feat2   = (float*)p; p += (size_t)cG * cHID * 4;
    float* gsum    = (float*)p; p += cHID * 4;
    float* gssq    = (float*)p; p += cHID * 4;
    __bf16* hb     = (__bf16*)p; p += (size_t)cN * cHID * 2;
    __bf16* WT     = (__bf16*)p; p += (size_t)6 * cHID * cHID * 2;

    // convert/transpose the 6 recurrent weight matrices to bf16 W^T
    for (int l = 0; l < 3; ++l) {
        k_wcvt<<<cHID, cHID, 0, stream>>>(Ws_r + (size_t)l * cHID * cHID,
                                          WT + (size_t)(2 * l) * cHID * cHID);
        k_wcvt<<<cHID, cHID, 0, stream>>>(Wd_r + (size_t)l * cHID * cHID,
                                          WT + (size_t)(2 * l + 1) * cHID * cHID);
    }

    // layer 0 projections (exact f32); res -> h buffer
    k_in_gemm<<<cN / 8, 256, 0, stream>>>(x, Ws0, bs0, Wd0, bd0, Wres0, fs, fd, h);

    for (int l = 0; l < 4; ++l) {
        if (l > 0) {
            k_gemm_mfma<<<dim3((cN / 16 + 3) / 4, 4), 256, 0, stream>>>(
                hb,
                WT + (size_t)(2 * (l - 1)) * cHID * cHID,
                WT + (size_t)(2 * (l - 1) + 1) * cHID * cHID,
                bs_r + (size_t)(l - 1) * cHID, bd_r + (size_t)(l - 1) * cHID,
                fs, fd);
        }
        const float* ap = (l == 0) ? a0 : a_r + (size_t)(l - 1) * cHID;
        k_edge<<<dim3(cG, 2), 256, 0, stream>>>(fs, fd, h, ap, src, dst,
                                                hpre, out + 1000 + l);
        (void)hipMemsetAsync(gsum, 0, 2 * cHID * 4, stream);
        k_bn_stats<<<cG, 256, 0, stream>>>(hpre, gsum, gssq);
        const float* gm = (l == 0) ? g0  : g_r  + (size_t)(l - 1) * cHID;
        const float* bt = (l == 0) ? be0 : be_r + (size_t)(l - 1) * cHID;
        k_bn_apply<<<cG, 256, 0, stream>>>(hpre, gsum, gssq, gm, bt, h, hb,
                                           featcat + (size_t)l * cHID);
    }

    k_fc1<<<cG, 256, 0, stream>>>(featcat, fc1_W, fc1_b, feat2);
    k_fc_bn<<<1, 256, 0, stream>>>(feat2, gfc, bfc);
    k_fc2<<<4, 256, 0, stream>>>(feat2, fc2_W, fc2_b, out);
}

// Round 4
// 616.996 us; speedup vs baseline: 3.0870x; 3.0870x over previous
//
#include <hip/hip_runtime.h>

typedef __bf16 bf16x8 __attribute__((ext_vector_type(8)));
typedef float f32x4 __attribute__((ext_vector_type(4)));

constexpr int cN   = 20000;   // nodes total
constexpr int cG   = 200;     // graphs
constexpr int cNPG = 100;     // nodes per graph
constexpr int cE   = 160000;  // edges total
constexpr int cEPG = 800;     // edges per graph
constexpr int cHID = 256;
constexpr int cIN  = 21;
constexpr float cEPS   = 1e-5f;
constexpr float cSLOPE = 0.2f;

// ---- layer-0: fs = x@Ws+bs, fd = x@Wd+bd, res = x@Wres  (K=21, f32 exact) ----
__global__ __launch_bounds__(256) void k_in_gemm(
    const float* __restrict__ x,
    const float* __restrict__ Ws, const float* __restrict__ bs,
    const float* __restrict__ Wd, const float* __restrict__ bd,
    const float* __restrict__ Wr,
    float* __restrict__ fs, float* __restrict__ fd, float* __restrict__ res)
{
    __shared__ float xl[8 * cIN];
    int tid = threadIdx.x;
    int rb  = blockIdx.x * 8;
    if (tid < 8 * cIN) xl[tid] = x[(size_t)rb * cIN + tid];
    __syncthreads();
    int j = tid;
    float ws[cIN], wd[cIN], wr[cIN];
#pragma unroll
    for (int k = 0; k < cIN; ++k) {
        ws[k] = Ws[k * cHID + j];
        wd[k] = Wd[k * cHID + j];
        wr[k] = Wr[k * cHID + j];
    }
    float vbs = bs[j], vbd = bd[j];
    for (int r = 0; r < 8; ++r) {
        float as = vbs, ad = vbd, ar = 0.f;
#pragma unroll
        for (int k = 0; k < cIN; ++k) {
            float xv = xl[r * cIN + k];
            as += xv * ws[k];
            ad += xv * wd[k];
            ar += xv * wr[k];
        }
        size_t o = (size_t)(rb + r) * cHID + j;
        fs[o] = as; fd[o] = ad; res[o] = ar;
    }
}

// ---- weight convert + transpose, all 6 matrices in one launch ----
// grid (cHID, 6): mat = 2*l + (0:Ws,1:Wd); WT[mat][n][k] = bf16(W[k][n])
__global__ __launch_bounds__(256) void k_wcvt(
    const float* __restrict__ Ws_r, const float* __restrict__ Wd_r,
    __bf16* __restrict__ WT)
{
    int mat = blockIdx.y;
    int l = mat >> 1;
    const float* W = ((mat & 1) ? Wd_r : Ws_r) + (size_t)l * cHID * cHID;
    __bf16* T = WT + (size_t)mat * cHID * cHID;
    int k = blockIdx.x, n = threadIdx.x;
    T[(size_t)n * cHID + k] = (__bf16)W[(size_t)k * cHID + n];
}

// ---- layers 1-3: fs = h@Ws+bs, fd = h@Wd+bd via bf16 MFMA, f32 accum ----
__global__ __launch_bounds__(256) void k_gemm_mfma(
    const __bf16* __restrict__ hb,
    const __bf16* __restrict__ WsT, const __bf16* __restrict__ WdT,
    const float* __restrict__ bs, const float* __restrict__ bd,
    float* __restrict__ fs, float* __restrict__ fd)
{
    int wave  = threadIdx.x >> 6;
    int lane  = threadIdx.x & 63;
    int strip = blockIdx.x * 4 + wave;        // 16-row strip
    if (strip >= cN / 16) return;
    int n0 = blockIdx.y * 64;                 // 64-col tile
    int rc = lane & 15;
    int kg = lane >> 4;
    int m0 = strip * 16;

    f32x4 accS[4], accD[4];
#pragma unroll
    for (int c = 0; c < 4; ++c) {
        accS[c] = (f32x4){0.f, 0.f, 0.f, 0.f};
        accD[c] = (f32x4){0.f, 0.f, 0.f, 0.f};
    }

    const __bf16* ap  = hb  + (size_t)(m0 + rc) * cHID + kg * 8;
    const __bf16* bsp = WsT + (size_t)(n0 + rc) * cHID + kg * 8;
    const __bf16* bdp = WdT + (size_t)(n0 + rc) * cHID + kg * 8;

#pragma unroll 2
    for (int k0 = 0; k0 < cHID; k0 += 32) {
        bf16x8 a = *(const bf16x8*)(ap + k0);
#pragma unroll
        for (int c = 0; c < 4; ++c) {
            bf16x8 bS = *(const bf16x8*)(bsp + (size_t)c * 16 * cHID + k0);
            bf16x8 bD = *(const bf16x8*)(bdp + (size_t)c * 16 * cHID + k0);
            accS[c] = __builtin_amdgcn_mfma_f32_16x16x32_bf16(a, bS, accS[c], 0, 0, 0);
            accD[c] = __builtin_amdgcn_mfma_f32_16x16x32_bf16(a, bD, accD[c], 0, 0, 0);
        }
    }
#pragma unroll
    for (int c = 0; c < 4; ++c) {
        int col = n0 + c * 16 + rc;
        float vbs = bs[col], vbd = bd[col];
#pragma unroll
        for (int i = 0; i < 4; ++i) {
            size_t o = (size_t)(m0 + kg * 4 + i) * cHID + col;
            fs[o] = accS[c][i] + vbs;
            fd[o] = accD[c][i] + vbd;
        }
    }
}

// ---- CSR build by dst (once per call; deterministic, no atomics) ----
// block per graph; graph g's CSR slots are [g*EPG, (g+1)*EPG)
__global__ __launch_bounds__(256) void k_csr(
    const int* __restrict__ dst, int* __restrict__ csr,
    int* __restrict__ off, int* __restrict__ deg)
{
    __shared__ int dstl[cEPG];
    __shared__ int cnts[128];
    int g = blockIdx.x, tid = threadIdx.x;
    int nb = g * cNPG, eb = g * cEPG;
    for (int i = tid; i < cEPG; i += 256) dstl[i] = dst[eb + i] - nb;
    __syncthreads();
    int cnt = 0;
    if (tid < cNPG) {
        for (int i = 0; i < cEPG; ++i) cnt += (dstl[i] == tid) ? 1 : 0;
    }
    if (tid < 128) cnts[tid] = (tid < cNPG) ? cnt : 0;
    __syncthreads();
    // Hillis-Steele inclusive scan over 128 entries (uniform control flow)
    for (int ofs = 1; ofs < 128; ofs <<= 1) {
        int t = 0;
        if (tid < 128 && tid >= ofs) t = cnts[tid - ofs];
        __syncthreads();
        if (tid < 128) cnts[tid] += t;
        __syncthreads();
    }
    if (tid < cNPG) {
        int base = cnts[tid] - cnt;   // exclusive
        off[nb + tid] = eb + base;
        deg[nb + tid] = cnt;
        int k = eb + base;
        for (int i = 0; i < cEPG; ++i)
            if (dstl[i] == tid) csr[k++] = eb + i;
    }
}

// ---- scores: 16 lanes per edge, float4 loads, 4-step shuffle reduce ----
__global__ __launch_bounds__(256) void k_score(
    const float* __restrict__ fs, const float* __restrict__ fd,
    const float* __restrict__ avec,
    const int* __restrict__ src, const int* __restrict__ dst,
    float* __restrict__ sco)
{
    int tid  = threadIdx.x;
    int lane = tid & 63, wave = tid >> 6;
    int grp  = lane >> 4, l = lane & 15;
    int e = blockIdx.x * 16 + wave * 4 + grp;
    int s = src[e], d = dst[e];
    const float* fsp = fs + (size_t)s * cHID;
    const float* fdp = fd + (size_t)d * cHID;
    float part = 0.f;
#pragma unroll
    for (int i = 0; i < 4; ++i) {
        int dim = l * 4 + i * 64;
        float4 a4 = *(const float4*)(avec + dim);
        float4 vs = *(const float4*)(fsp + dim);
        float4 vd = *(const float4*)(fdp + dim);
        float v0 = vs.x + vd.x, v1 = vs.y + vd.y;
        float v2 = vs.z + vd.z, v3 = vs.w + vd.w;
        v0 = v0 > 0.f ? v0 : cSLOPE * v0;
        v1 = v1 > 0.f ? v1 : cSLOPE * v1;
        v2 = v2 > 0.f ? v2 : cSLOPE * v2;
        v3 = v3 > 0.f ? v3 : cSLOPE * v3;
        part += v0 * a4.x + v1 * a4.y + v2 * a4.z + v3 * a4.w;
    }
    part += __shfl_xor(part, 1);
    part += __shfl_xor(part, 2);
    part += __shfl_xor(part, 4);
    part += __shfl_xor(part, 8);
    if (l == 0) sco[e] = part;
}

// ---- per-dst softmax + aggregation: wave per node, no atomics ----
__global__ __launch_bounds__(256) void k_aggr(
    const float* __restrict__ fs, const float* __restrict__ res,
    const float* __restrict__ sco, const int* __restrict__ csr,
    const int* __restrict__ off, const int* __restrict__ deg,
    const int* __restrict__ src,
    float* __restrict__ hpre, float* __restrict__ attn_out)
{
    __shared__ float albuf[4][128];
    int tid = threadIdx.x, lane = tid & 63, wave = tid >> 6;
    int n = blockIdx.x * 4 + wave;
    int dg = deg[n], base = off[n];

    float m = -3.4e38f, den = 0.f;
    for (int i = lane; i < dg; i += 64) m = fmaxf(m, sco[csr[base + i]]);
#pragma unroll
    for (int o = 32; o; o >>= 1) m = fmaxf(m, __shfl_xor(m, o));
    for (int i = lane; i < dg; i += 64) den += __expf(sco[csr[base + i]] - m);
#pragma unroll
    for (int o = 32; o; o >>= 1) den += __shfl_xor(den, o);
    float inv = (dg > 0) ? 1.f / den : 0.f;

    for (int i = lane; i < dg; i += 64) {
        int e = csr[base + i];
        float al = __expf(sco[e] - m) * inv;
        if (i < 128) albuf[wave][i] = al;
        attn_out[(size_t)e * 4] = al;
    }
    __syncthreads();

    float4 acc = {0.f, 0.f, 0.f, 0.f};
    for (int i = 0; i < dg; ++i) {
        int e = csr[base + i];
        int s = src[e];
        float al = (i < 128) ? albuf[wave][i] : __expf(sco[e] - m) * inv;
        float4 f4 = *(const float4*)(fs + (size_t)s * cHID + lane * 4);
        acc.x += al * f4.x; acc.y += al * f4.y;
        acc.z += al * f4.z; acc.w += al * f4.w;
    }
    float4 r4 = *(const float4*)(res + (size_t)n * cHID + lane * 4);
    float4 o4 = {acc.x + r4.x, acc.y + r4.y, acc.z + r4.z, acc.w + r4.w};
    *(float4*)(hpre + (size_t)n * cHID + lane * 4) = o4;
}

// ---- BN stats: column sums / sumsq over all 20000 rows ----
__global__ __launch_bounds__(256) void k_bn_stats(
    const float* __restrict__ hpre, float* __restrict__ gsum, float* __restrict__ gssq)
{
    int j = threadIdx.x;
    int rb = blockIdx.x * cNPG;
    float s = 0.f, q = 0.f;
    for (int r = 0; r < cNPG; ++r) {
        float v = hpre[(size_t)(rb + r) * cHID + j];
        s += v; q += v * v;
    }
    atomicAdd(&gsum[j], s);
    atomicAdd(&gssq[j], q);
}

// ---- BN apply + ReLU + graph mean; emit f32 h and bf16 h ----
__global__ __launch_bounds__(256) void k_bn_apply(
    const float* __restrict__ hpre,
    const float* __restrict__ gsum, const float* __restrict__ gssq,
    const float* __restrict__ gamma, const float* __restrict__ beta,
    float* __restrict__ h, __bf16* __restrict__ hb, float* __restrict__ featcat)
{
    int j = threadIdx.x, g = blockIdx.x;
    float mu  = gsum[j] * (1.f / cN);
    float var = gssq[j] * (1.f / cN) - mu * mu;
    float sc  = gamma[j] * rsqrtf(var + cEPS);
    float sh  = beta[j] - mu * sc;
    float fsum = 0.f;
    for (int r = 0; r < cNPG; ++r) {
        size_t i = (size_t)(g * cNPG + r) * cHID + j;
        float v = hpre[i] * sc + sh;
        v = v > 0.f ? v : 0.f;
        h[i] = v;
        hb[i] = (__bf16)v;
        fsum += v;
    }
    featcat[(size_t)g * (4 * cHID) + j] = fsum * (1.f / cNPG);
}

// ---- head: feat2 = featcat @ fc1_W + fc1_b ----
__global__ __launch_bounds__(256) void k_fc1(
    const float* __restrict__ featcat, const float* __restrict__ W,
    const float* __restrict__ b, float* __restrict__ out)
{
    __shared__ float row[4 * cHID];
    int g = blockIdx.x, j = threadIdx.x;
    for (int i = j; i < 4 * cHID; i += 256) row[i] = featcat[(size_t)g * (4 * cHID) + i];
    __syncthreads();
    float acc = b[j];
    for (int k = 0; k < 4 * cHID; ++k) acc += row[k] * W[(size_t)k * cHID + j];
    out[(size_t)g * cHID + j] = acc;
}

// ---- head BN (over 200 rows) + ReLU, in place ----
__global__ __launch_bounds__(256) void k_fc_bn(
    float* __restrict__ f2, const float* __restrict__ gamma, const float* __restrict__ beta)
{
    int j = threadIdx.x;
    float s = 0.f, q = 0.f;
    for (int r = 0; r < cG; ++r) { float v = f2[(size_t)r * cHID + j]; s += v; q += v * v; }
    float mu  = s * (1.f / cG);
    float var = q * (1.f / cG) - mu * mu;
    float sc  = gamma[j] * rsqrtf(var + cEPS);
    float sh  = beta[j] - mu * sc;
    for (int r = 0; r < cG; ++r) {
        float v = f2[(size_t)r * cHID + j] * sc + sh;
        f2[(size_t)r * cHID + j] = v > 0.f ? v : 0.f;
    }
}

// ---- head: out[r*5+o] = feat2[r] . fc2_W[:,o] + fc2_b[o] ----
__global__ __launch_bounds__(256) void k_fc2(
    const float* __restrict__ f2, const float* __restrict__ W,
    const float* __restrict__ b, float* __restrict__ out)
{
    int t = blockIdx.x * 256 + threadIdx.x;
    if (t >= cG * 5) return;
    int r = t / 5, o = t % 5;
    float acc = b[o];
    for (int k = 0; k < cHID; ++k) acc += f2[(size_t)r * cHID + k] * W[k * 5 + o];
    out[t] = acc;
}

extern "C" void kernel_launch(void* const* d_in, const int* in_sizes, int n_in,
                              void* d_out, int out_size, void* d_ws, size_t ws_size,
                              hipStream_t stream)
{
    (void)in_sizes; (void)n_in; (void)out_size; (void)ws_size;
    const float* x     = (const float*)d_in[0];
    const float* Ws0   = (const float*)d_in[1];
    const float* bs0   = (const float*)d_in[2];
    const float* Wd0   = (const float*)d_in[3];
    const float* bd0   = (const float*)d_in[4];
    const float* a0    = (const float*)d_in[5];
    const float* Wres0 = (const float*)d_in[6];
    const float* g0    = (const float*)d_in[7];
    const float* be0   = (const float*)d_in[8];
    const float* Ws_r  = (const float*)d_in[9];
    const float* bs_r  = (const float*)d_in[10];
    const float* Wd_r  = (const float*)d_in[11];
    const float* bd_r  = (const float*)d_in[12];
    const float* a_r   = (const float*)d_in[13];
    const float* g_r   = (const float*)d_in[14];
    const float* be_r  = (const float*)d_in[15];
    const float* fc1_W = (const float*)d_in[16];
    const float* fc1_b = (const float*)d_in[17];
    const float* gfc   = (const float*)d_in[18];
    const float* bfc   = (const float*)d_in[19];
    const float* fc2_W = (const float*)d_in[20];
    const float* fc2_b = (const float*)d_in[21];
    const int*   src   = (const int*)d_in[22];
    const int*   dst   = (const int*)d_in[23];
    float* out = (float*)d_out;

    char* p = (char*)d_ws;
    float* h       = (float*)p; p += (size_t)cN * cHID * 4;
    float* fs      = (float*)p; p += (size_t)cN * cHID * 4;
    float* fd      = (float*)p; p += (size_t)cN * cHID * 4;
    float* hpre    = (float*)p; p += (size_t)cN * cHID * 4;
    float* featcat = (float*)p; p += (size_t)cG * 4 * cHID * 4;
    float* feat2   = (float*)p; p += (size_t)cG * cHID * 4;
    float* gsum    = (float*)p; p += cHID * 4;
    float* gssq    = (float*)p; p += cHID * 4;
    float* sco     = (float*)p; p += (size_t)cE * 4;
    int*   csr     = (int*)p;   p += (size_t)cE * 4;
    int*   offv    = (int*)p;   p += (size_t)cN * 4;
    int*   degv    = (int*)p;   p += (size_t)cN * 4;
    __bf16* hb     = (__bf16*)p; p += (size_t)cN * cHID * 2;
    __bf16* WT     = (__bf16*)p; p += (size_t)6 * cHID * cHID * 2;

    // one-time setup: weight convert/transpose + CSR by dst
    k_wcvt<<<dim3(cHID, 6), 256, 0, stream>>>(Ws_r, Wd_r, WT);
    k_csr<<<cG, 256, 0, stream>>>(dst, csr, offv, degv);

    // layer 0 projections (exact f32); res -> h buffer
    k_in_gemm<<<cN / 8, 256, 0, stream>>>(x, Ws0, bs0, Wd0, bd0, Wres0, fs, fd, h);

    for (int l = 0; l < 4; ++l) {
        if (l > 0) {
            k_gemm_mfma<<<dim3((cN / 16 + 3) / 4, 4), 256, 0, stream>>>(
                hb,
                WT + (size_t)(2 * (l - 1)) * cHID * cHID,
                WT + (size_t)(2 * (l - 1) + 1) * cHID * cHID,
                bs_r + (size_t)(l - 1) * cHID, bd_r + (size_t)(l - 1) * cHID,
                fs, fd);
        }
        const float* ap = (l == 0) ? a0 : a_r + (size_t)(l - 1) * cHID;
        k_score<<<cE / 16, 256, 0, stream>>>(fs, fd, ap, src, dst, sco);
        k_aggr<<<cN / 4, 256, 0, stream>>>(fs, h, sco, csr, offv, degv, src,
                                           hpre, out + 1000 + l);
        (void)hipMemsetAsync(gsum, 0, 2 * cHID * 4, stream);
        k_bn_stats<<<cG, 256, 0, stream>>>(hpre, gsum, gssq);
        const float* gm = (l == 0) ? g0  : g_r  + (size_t)(l - 1) * cHID;
        const float* bt = (l == 0) ? be0 : be_r + (size_t)(l - 1) * cHID;
        k_bn_apply<<<cG, 256, 0, stream>>>(hpre, gsum, gssq, gm, bt, h, hb,
                                           featcat + (size_t)l * cHID);
    }

    k_fc1<<<cG, 256, 0, stream>>>(featcat, fc1_W, fc1_b, feat2);
    k_fc_bn<<<1, 256, 0, stream>>>(feat2, gfc, bfc);
    k_fc2<<<4, 256, 0, stream>>>(feat2, fc2_W, fc2_b, out);
}

// Round 6
// 519.383 us; speedup vs baseline: 3.6671x; 1.1879x over previous
//
#include <hip/hip_runtime.h>

typedef __bf16 bf16x8 __attribute__((ext_vector_type(8)));
typedef __bf16 bf16x4 __attribute__((ext_vector_type(4)));
typedef float f32x4 __attribute__((ext_vector_type(4)));

constexpr int cN   = 20000;   // nodes total
constexpr int cG   = 200;     // graphs
constexpr int cNPG = 100;     // nodes per graph
constexpr int cE   = 160000;  // edges total
constexpr int cEPG = 800;     // edges per graph
constexpr int cHID = 256;
constexpr int cIN  = 21;
constexpr float cEPS   = 1e-5f;
constexpr float cSLOPE = 0.2f;
constexpr int cCH  = 32;      // csr chunks per graph
constexpr int cCHS = 25;      // edges per chunk

__device__ __forceinline__ float4 cvt4(bf16x4 v) {
    return make_float4((float)v.x, (float)v.y, (float)v.z, (float)v.w);
}

// ---- layer-0: fsb/fdb = bf16(x@W+b), res = x@Wres (f32) ----
__global__ __launch_bounds__(256) void k_in_gemm(
    const float* __restrict__ x,
    const float* __restrict__ Ws, const float* __restrict__ bs,
    const float* __restrict__ Wd, const float* __restrict__ bd,
    const float* __restrict__ Wr,
    __bf16* __restrict__ fsb, __bf16* __restrict__ fdb, float* __restrict__ res)
{
    __shared__ float xl[8 * cIN];
    int tid = threadIdx.x;
    int rb  = blockIdx.x * 8;
    if (tid < 8 * cIN) xl[tid] = x[(size_t)rb * cIN + tid];
    __syncthreads();
    int j = tid;
    float ws[cIN], wd[cIN], wr[cIN];
#pragma unroll
    for (int k = 0; k < cIN; ++k) {
        ws[k] = Ws[k * cHID + j];
        wd[k] = Wd[k * cHID + j];
        wr[k] = Wr[k * cHID + j];
    }
    float vbs = bs[j], vbd = bd[j];
    for (int r = 0; r < 8; ++r) {
        float as = vbs, ad = vbd, ar = 0.f;
#pragma unroll
        for (int k = 0; k < cIN; ++k) {
            float xv = xl[r * cIN + k];
            as += xv * ws[k];
            ad += xv * wd[k];
            ar += xv * wr[k];
        }
        size_t o = (size_t)(rb + r) * cHID + j;
        fsb[o] = (__bf16)as; fdb[o] = (__bf16)ad; res[o] = ar;
    }
}

// ---- weight convert + transpose, all 6 matrices in one launch ----
__global__ __launch_bounds__(256) void k_wcvt(
    const float* __restrict__ Ws_r, const float* __restrict__ Wd_r,
    __bf16* __restrict__ WT)
{
    int mat = blockIdx.y;
    int l = mat >> 1;
    const float* W = ((mat & 1) ? Wd_r : Ws_r) + (size_t)l * cHID * cHID;
    __bf16* T = WT + (size_t)mat * cHID * cHID;
    int k = blockIdx.x, n = threadIdx.x;
    T[(size_t)n * cHID + k] = (__bf16)W[(size_t)k * cHID + n];
}

// ---- layers 1-3: fsb = bf16(h@Ws+bs), fdb = bf16(h@Wd+bd) via MFMA ----
__global__ __launch_bounds__(256) void k_gemm_mfma(
    const __bf16* __restrict__ hb,
    const __bf16* __restrict__ WsT, const __bf16* __restrict__ WdT,
    const float* __restrict__ bs, const float* __restrict__ bd,
    __bf16* __restrict__ fsb, __bf16* __restrict__ fdb)
{
    int wave  = threadIdx.x >> 6;
    int lane  = threadIdx.x & 63;
    int strip = blockIdx.x * 4 + wave;        // 16-row strip
    if (strip >= cN / 16) return;
    int n0 = blockIdx.y * 64;                 // 64-col tile
    int rc = lane & 15;
    int kg = lane >> 4;
    int m0 = strip * 16;

    f32x4 accS[4], accD[4];
#pragma unroll
    for (int c = 0; c < 4; ++c) {
        accS[c] = (f32x4){0.f, 0.f, 0.f, 0.f};
        accD[c] = (f32x4){0.f, 0.f, 0.f, 0.f};
    }

    const __bf16* ap  = hb  + (size_t)(m0 + rc) * cHID + kg * 8;
    const __bf16* bsp = WsT + (size_t)(n0 + rc) * cHID + kg * 8;
    const __bf16* bdp = WdT + (size_t)(n0 + rc) * cHID + kg * 8;

#pragma unroll 2
    for (int k0 = 0; k0 < cHID; k0 += 32) {
        bf16x8 a = *(const bf16x8*)(ap + k0);
#pragma unroll
        for (int c = 0; c < 4; ++c) {
            bf16x8 bS = *(const bf16x8*)(bsp + (size_t)c * 16 * cHID + k0);
            bf16x8 bD = *(const bf16x8*)(bdp + (size_t)c * 16 * cHID + k0);
            accS[c] = __builtin_amdgcn_mfma_f32_16x16x32_bf16(a, bS, accS[c], 0, 0, 0);
            accD[c] = __builtin_amdgcn_mfma_f32_16x16x32_bf16(a, bD, accD[c], 0, 0, 0);
        }
    }
#pragma unroll
    for (int c = 0; c < 4; ++c) {
        int col = n0 + c * 16 + rc;
        float vbs = bs[col], vbd = bd[col];
#pragma unroll
        for (int i = 0; i < 4; ++i) {
            size_t o = (size_t)(m0 + kg * 4 + i) * cHID + col;
            fsb[o] = (__bf16)(accS[c][i] + vbs);
            fdb[o] = (__bf16)(accD[c][i] + vbd);
        }
    }
}

// ---- CSR build by dst: chunked stable counting sort (deterministic) ----
__global__ __launch_bounds__(256) void k_csr(
    const int* __restrict__ dst, int* __restrict__ csr,
    int* __restrict__ off, int* __restrict__ deg)
{
    __shared__ int dstl[cEPG];
    __shared__ int cnt[cCH * 128];     // [chunk][node] (128-padded rows)
    __shared__ int offl[cNPG];
    __shared__ int tot[128];
    int g = blockIdx.x, tid = threadIdx.x;
    int nb = g * cNPG, eb = g * cEPG;

    for (int i = tid; i < cEPG; i += 256) dstl[i] = dst[eb + i] - nb;
    for (int i = tid; i < cCH * 128; i += 256) cnt[i] = 0;
    __syncthreads();

    // per-(node,chunk) histogram (order-independent => deterministic)
    for (int i = tid; i < cEPG; i += 256)
        atomicAdd(&cnt[(i / cCHS) * 128 + dstl[i]], 1);
    __syncthreads();

    // per-node exclusive scan over chunks; node totals
    int mytot = 0;
    if (tid < cNPG) {
        int run = 0;
        for (int c = 0; c < cCH; ++c) {
            int t = cnt[c * 128 + tid];
            cnt[c * 128 + tid] = run;
            run += t;
        }
        mytot = run;
    }
    if (tid < 128) tot[tid] = (tid < cNPG) ? mytot : 0;
    __syncthreads();
    // Hillis-Steele inclusive scan over nodes
    for (int ofs = 1; ofs < 128; ofs <<= 1) {
        int t = 0;
        if (tid < 128 && tid >= ofs) t = tot[tid - ofs];
        __syncthreads();
        if (tid < 128) tot[tid] += t;
        __syncthreads();
    }
    if (tid < cNPG) {
        int excl = tot[tid] - mytot;
        offl[tid] = excl;
        off[nb + tid] = eb + excl;
        deg[nb + tid] = mytot;
    }
    __syncthreads();

    // stable write: thread per chunk, serial in edge order within chunk
    if (tid < cCH) {
        for (int j = 0; j < cCHS; ++j) {
            int i = tid * cCHS + j;
            int n = dstl[i];
            int k = cnt[tid * 128 + n]++;
            csr[eb + offl[n] + k] = eb + i;
        }
    }
}

// ---- fused edge stage: scores + softmax + weighted gather, wave/node ----
__global__ __launch_bounds__(256) void k_edge2(
    const __bf16* __restrict__ fsb, const __bf16* __restrict__ fdb,
    const float* __restrict__ res, const float* __restrict__ avec,
    const int* __restrict__ csr, const int* __restrict__ off,
    const int* __restrict__ deg, const int* __restrict__ src,
    float* __restrict__ hpre, float* __restrict__ attn_out,
    float* __restrict__ sco_spill, float* __restrict__ bnz)
{
    __shared__ float scob[4][64];
    __shared__ float albuf[4][64];
    int tid = threadIdx.x, lane = tid & 63, w = tid >> 6;
    if (blockIdx.x == 0) {                      // zero BN accumulators (512 floats)
        bnz[tid] = 0.f;
        bnz[tid + 256] = 0.f;
    }
    int n = blockIdx.x * 4 + w;
    int dg = deg[n], base = off[n];

    float4 a4  = *(const float4*)(avec + lane * 4);
    float4 fd4 = cvt4(*(const bf16x4*)(fdb + (size_t)n * cHID + lane * 4));

    // phase A: scores per in-edge (fd row reused from registers)
    float m = -3.4e38f;
    for (int i = 0; i < dg; ++i) {
        int e = csr[base + i];
        int s = src[e];
        float4 f4 = cvt4(*(const bf16x4*)(fsb + (size_t)s * cHID + lane * 4));
        float v0 = f4.x + fd4.x, v1 = f4.y + fd4.y;
        float v2 = f4.z + fd4.z, v3 = f4.w + fd4.w;
        v0 = v0 > 0.f ? v0 : cSLOPE * v0;
        v1 = v1 > 0.f ? v1 : cSLOPE * v1;
        v2 = v2 > 0.f ? v2 : cSLOPE * v2;
        v3 = v3 > 0.f ? v3 : cSLOPE * v3;
        float part = v0 * a4.x + v1 * a4.y + v2 * a4.z + v3 * a4.w;
#pragma unroll
        for (int o = 32; o; o >>= 1) part += __shfl_xor(part, o);
        if (i < 64) { if (lane == 0) scob[w][i] = part; }
        else        { if (lane == 0) sco_spill[e] = part; }
        m = fmaxf(m, part);
    }

    // softmax denominator
    float den = 0.f;
    for (int i = lane; i < dg; i += 64) {
        float sv = (i < 64) ? scob[w][i] : sco_spill[csr[base + i]];
        den += __expf(sv - m);
    }
#pragma unroll
    for (int o = 32; o; o >>= 1) den += __shfl_xor(den, o);
    float inv = (dg > 0) ? 1.f / den : 0.f;

    // alpha: stash + attn output
    for (int i = lane; i < dg; i += 64) {
        int e = csr[base + i];
        float sv = (i < 64) ? scob[w][i] : sco_spill[e];
        float al = __expf(sv - m) * inv;
        if (i < 64) albuf[w][i] = al; else sco_spill[e] = al;
        attn_out[(size_t)e * 4] = al;
    }

    // phase B: weighted gather + residual
    float4 acc = {0.f, 0.f, 0.f, 0.f};
    for (int i = 0; i < dg; ++i) {
        int e = csr[base + i];
        int s = src[e];
        float al = (i < 64) ? albuf[w][i] : sco_spill[e];
        float4 f4 = cvt4(*(const bf16x4*)(fsb + (size_t)s * cHID + lane * 4));
        acc.x += al * f4.x; acc.y += al * f4.y;
        acc.z += al * f4.z; acc.w += al * f4.w;
    }
    float4 r4 = *(const float4*)(res + (size_t)n * cHID + lane * 4);
    float4 o4 = {acc.x + r4.x, acc.y + r4.y, acc.z + r4.z, acc.w + r4.w};
    *(float4*)(hpre + (size_t)n * cHID + lane * 4) = o4;
}

// ---- BN stats: column sums / sumsq over all 20000 rows ----
__global__ __launch_bounds__(256) void k_bn_stats(
    const float* __restrict__ hpre, float* __restrict__ gsum, float* __restrict__ gssq)
{
    int j = threadIdx.x;
    int rb = blockIdx.x * cNPG;
    float s = 0.f, q = 0.f;
    for (int r = 0; r < cNPG; ++r) {
        float v = hpre[(size_t)(rb + r) * cHID + j];
        s += v; q += v * v;
    }
    atomicAdd(&gsum[j], s);
    atomicAdd(&gssq[j], q);
}

// ---- BN apply + ReLU + graph mean; emit f32 h and bf16 h ----
__global__ __launch_bounds__(256) void k_bn_apply(
    const float* __restrict__ hpre,
    const float* __restrict__ gsum, const float* __restrict__ gssq,
    const float* __restrict__ gamma, const float* __restrict__ beta,
    float* __restrict__ h, __bf16* __restrict__ hb, float* __restrict__ featcat)
{
    int j = threadIdx.x, g = blockIdx.x;
    float mu  = gsum[j] * (1.f / cN);
    float var = gssq[j] * (1.f / cN) - mu * mu;
    float sc  = gamma[j] * rsqrtf(var + cEPS);
    float sh  = beta[j] - mu * sc;
    float fsum = 0.f;
    for (int r = 0; r < cNPG; ++r) {
        size_t i = (size_t)(g * cNPG + r) * cHID + j;
        float v = hpre[i] * sc + sh;
        v = v > 0.f ? v : 0.f;
        h[i] = v;
        hb[i] = (__bf16)v;
        fsum += v;
    }
    featcat[(size_t)g * (4 * cHID) + j] = fsum * (1.f / cNPG);
}

// ---- head: feat2 = featcat @ fc1_W + fc1_b ----
__global__ __launch_bounds__(256) void k_fc1(
    const float* __restrict__ featcat, const float* __restrict__ W,
    const float* __restrict__ b, float* __restrict__ out)
{
    __shared__ float row[4 * cHID];
    int g = blockIdx.x, j = threadIdx.x;
    for (int i = j; i < 4 * cHID; i += 256) row[i] = featcat[(size_t)g * (4 * cHID) + i];
    __syncthreads();
    float acc = b[j];
    for (int k = 0; k < 4 * cHID; ++k) acc += row[k] * W[(size_t)k * cHID + j];
    out[(size_t)g * cHID + j] = acc;
}

// ---- head BN (over 200 rows) + ReLU, in place ----
__global__ __launch_bounds__(256) void k_fc_bn(
    float* __restrict__ f2, const float* __restrict__ gamma, const float* __restrict__ beta)
{
    int j = threadIdx.x;
    float s = 0.f, q = 0.f;
    for (int r = 0; r < cG; ++r) { float v = f2[(size_t)r * cHID + j]; s += v; q += v * v; }
    float mu  = s * (1.f / cG);
    float var = q * (1.f / cG) - mu * mu;
    float sc  = gamma[j] * rsqrtf(var + cEPS);
    float sh  = beta[j] - mu * sc;
    for (int r = 0; r < cG; ++r) {
        float v = f2[(size_t)r * cHID + j] * sc + sh;
        f2[(size_t)r * cHID + j] = v > 0.f ? v : 0.f;
    }
}

// ---- head: out[r*5+o] = feat2[r] . fc2_W[:,o] + fc2_b[o] ----
__global__ __launch_bounds__(256) void k_fc2(
    const float* __restrict__ f2, const float* __restrict__ W,
    const float* __restrict__ b, float* __restrict__ out)
{
    int t = blockIdx.x * 256 + threadIdx.x;
    if (t >= cG * 5) return;
    int r = t / 5, o = t % 5;
    float acc = b[o];
    for (int k = 0; k < cHID; ++k) acc += f2[(size_t)r * cHID + k] * W[k * 5 + o];
    out[t] = acc;
}

extern "C" void kernel_launch(void* const* d_in, const int* in_sizes, int n_in,
                              void* d_out, int out_size, void* d_ws, size_t ws_size,
                              hipStream_t stream)
{
    (void)in_sizes; (void)n_in; (void)out_size; (void)ws_size;
    const float* x     = (const float*)d_in[0];
    const float* Ws0   = (const float*)d_in[1];
    const float* bs0   = (const float*)d_in[2];
    const float* Wd0   = (const float*)d_in[3];
    const float* bd0   = (const float*)d_in[4];
    const float* a0    = (const float*)d_in[5];
    const float* Wres0 = (const float*)d_in[6];
    const float* g0    = (const float*)d_in[7];
    const float* be0   = (const float*)d_in[8];
    const float* Ws_r  = (const float*)d_in[9];
    const float* bs_r  = (const float*)d_in[10];
    const float* Wd_r  = (const float*)d_in[11];
    const float* bd_r  = (const float*)d_in[12];
    const float* a_r   = (const float*)d_in[13];
    const float* g_r   = (const float*)d_in[14];
    const float* be_r  = (const float*)d_in[15];
    const float* fc1_W = (const float*)d_in[16];
    const float* fc1_b = (const float*)d_in[17];
    const float* gfc   = (const float*)d_in[18];
    const float* bfc   = (const float*)d_in[19];
    const float* fc2_W = (const float*)d_in[20];
    const float* fc2_b = (const float*)d_in[21];
    const int*   src   = (const int*)d_in[22];
    const int*   dst   = (const int*)d_in[23];
    float* out = (float*)d_out;

    char* p = (char*)d_ws;
    float* h       = (float*)p; p += (size_t)cN * cHID * 4;
    float* hpre    = (float*)p; p += (size_t)cN * cHID * 4;
    float* featcat = (float*)p; p += (size_t)cG * 4 * cHID * 4;
    float* feat2   = (float*)p; p += (size_t)cG * cHID * 4;
    float* gsum    = (float*)p; p += cHID * 4;
    float* gssq    = (float*)p; p += cHID * 4;
    float* sco     = (float*)p; p += (size_t)cE * 4;
    int*   csr     = (int*)p;   p += (size_t)cE * 4;
    int*   offv    = (int*)p;   p += (size_t)cN * 4;
    int*   degv    = (int*)p;   p += (size_t)cN * 4;
    __bf16* hb     = (__bf16*)p; p += (size_t)cN * cHID * 2;
    __bf16* fsb    = (__bf16*)p; p += (size_t)cN * cHID * 2;
    __bf16* fdb    = (__bf16*)p; p += (size_t)cN * cHID * 2;
    __bf16* WT     = (__bf16*)p; p += (size_t)6 * cHID * cHID * 2;

    // one-time setup: weight convert/transpose + CSR by dst
    k_wcvt<<<dim3(cHID, 6), 256, 0, stream>>>(Ws_r, Wd_r, WT);
    k_csr<<<cG, 256, 0, stream>>>(dst, csr, offv, degv);

    // layer 0 projections (f32 math, bf16 feature emit); res -> h buffer
    k_in_gemm<<<cN / 8, 256, 0, stream>>>(x, Ws0, bs0, Wd0, bd0, Wres0, fsb, fdb, h);

    for (int l = 0; l < 4; ++l) {
        if (l > 0) {
            k_gemm_mfma<<<dim3((cN / 16 + 3) / 4, 4), 256, 0, stream>>>(
                hb,
                WT + (size_t)(2 * (l - 1)) * cHID * cHID,
                WT + (size_t)(2 * (l - 1) + 1) * cHID * cHID,
                bs_r + (size_t)(l - 1) * cHID, bd_r + (size_t)(l - 1) * cHID,
                fsb, fdb);
        }
        const float* ap = (l == 0) ? a0 : a_r + (size_t)(l - 1) * cHID;
        k_edge2<<<cN / 4, 256, 0, stream>>>(fsb, fdb, h, ap, csr, offv, degv, src,
                                            hpre, out + 1000 + l, sco, gsum);
        k_bn_stats<<<cG, 256, 0, stream>>>(hpre, gsum, gssq);
        const float* gm = (l == 0) ? g0  : g_r  + (size_t)(l - 1) * cHID;
        const float* bt = (l == 0) ? be0 : be_r + (size_t)(l - 1) * cHID;
        k_bn_apply<<<cG, 256, 0, stream>>>(hpre, gsum, gssq, gm, bt, h, hb,
                                           featcat + (size_t)l * cHID);
    }

    k_fc1<<<cG, 256, 0, stream>>>(featcat, fc1_W, fc1_b, feat2);
    k_fc_bn<<<1, 256, 0, stream>>>(feat2, gfc, bfc);
    k_fc2<<<4, 256, 0, stream>>>(feat2, fc2_W, fc2_b, out);
}

// Round 7
// 438.336 us; speedup vs baseline: 4.3452x; 1.1849x over previous
//
#include <hip/hip_runtime.h>

typedef __bf16 bf16x8 __attribute__((ext_vector_type(8)));
typedef __bf16 bf16x4 __attribute__((ext_vector_type(4)));
typedef float f32x4 __attribute__((ext_vector_type(4)));

constexpr int cN   = 20000;   // nodes total
constexpr int cG   = 200;     // graphs
constexpr int cNPG = 100;     // nodes per graph
constexpr int cE   = 160000;  // edges total
constexpr int cEPG = 800;     // edges per graph
constexpr int cHID = 256;
constexpr int cIN  = 21;
constexpr float cEPS   = 1e-5f;
constexpr float cSLOPE = 0.2f;
constexpr int cCH  = 32;      // csr chunks per graph
constexpr int cCHS = 25;      // edges per chunk

__device__ __forceinline__ float4 cvt4(bf16x4 v) {
    return make_float4((float)v.x, (float)v.y, (float)v.z, (float)v.w);
}

// ---- layer-0: fsb/fdb = bf16(x@W+b), resb = bf16(x@Wres) ----
__global__ __launch_bounds__(256) void k_in_gemm(
    const float* __restrict__ x,
    const float* __restrict__ Ws, const float* __restrict__ bs,
    const float* __restrict__ Wd, const float* __restrict__ bd,
    const float* __restrict__ Wr,
    __bf16* __restrict__ fsb, __bf16* __restrict__ fdb, __bf16* __restrict__ resb)
{
    __shared__ float xl[8 * cIN];
    int tid = threadIdx.x;
    int rb  = blockIdx.x * 8;
    if (tid < 8 * cIN) xl[tid] = x[(size_t)rb * cIN + tid];
    __syncthreads();
    int j = tid;
    float ws[cIN], wd[cIN], wr[cIN];
#pragma unroll
    for (int k = 0; k < cIN; ++k) {
        ws[k] = Ws[k * cHID + j];
        wd[k] = Wd[k * cHID + j];
        wr[k] = Wr[k * cHID + j];
    }
    float vbs = bs[j], vbd = bd[j];
    for (int r = 0; r < 8; ++r) {
        float as = vbs, ad = vbd, ar = 0.f;
#pragma unroll
        for (int k = 0; k < cIN; ++k) {
            float xv = xl[r * cIN + k];
            as += xv * ws[k];
            ad += xv * wd[k];
            ar += xv * wr[k];
        }
        size_t o = (size_t)(rb + r) * cHID + j;
        fsb[o] = (__bf16)as; fdb[o] = (__bf16)ad; resb[o] = (__bf16)ar;
    }
}

// ---- weight convert + transpose, all 6 matrices in one launch ----
__global__ __launch_bounds__(256) void k_wcvt(
    const float* __restrict__ Ws_r, const float* __restrict__ Wd_r,
    __bf16* __restrict__ WT)
{
    int mat = blockIdx.y;
    int l = mat >> 1;
    const float* W = ((mat & 1) ? Wd_r : Ws_r) + (size_t)l * cHID * cHID;
    __bf16* T = WT + (size_t)mat * cHID * cHID;
    int k = blockIdx.x, n = threadIdx.x;
    T[(size_t)n * cHID + k] = (__bf16)W[(size_t)k * cHID + n];
}

// ---- layers 1-3: fsb/fdb via MFMA; 32 rows per wave (2 A-frags share B) ----
__global__ __launch_bounds__(256) void k_gemm_mfma(
    const __bf16* __restrict__ hb,
    const __bf16* __restrict__ WsT, const __bf16* __restrict__ WdT,
    const float* __restrict__ bs, const float* __restrict__ bd,
    __bf16* __restrict__ fsb, __bf16* __restrict__ fdb)
{
    int wave  = threadIdx.x >> 6;
    int lane  = threadIdx.x & 63;
    int strip = blockIdx.x * 4 + wave;        // 32-row strip
    if (strip >= cN / 32) return;
    int n0 = blockIdx.y * 64;                 // 64-col tile
    int rc = lane & 15;
    int kg = lane >> 4;
    int m0 = strip * 32;

    f32x4 accS[2][4], accD[2][4];
#pragma unroll
    for (int r = 0; r < 2; ++r)
#pragma unroll
        for (int c = 0; c < 4; ++c) {
            accS[r][c] = (f32x4){0.f, 0.f, 0.f, 0.f};
            accD[r][c] = (f32x4){0.f, 0.f, 0.f, 0.f};
        }

    const __bf16* ap  = hb  + (size_t)(m0 + rc) * cHID + kg * 8;
    const __bf16* bsp = WsT + (size_t)(n0 + rc) * cHID + kg * 8;
    const __bf16* bdp = WdT + (size_t)(n0 + rc) * cHID + kg * 8;

#pragma unroll 2
    for (int k0 = 0; k0 < cHID; k0 += 32) {
        bf16x8 a0 = *(const bf16x8*)(ap + k0);
        bf16x8 a1 = *(const bf16x8*)(ap + 16 * cHID + k0);
#pragma unroll
        for (int c = 0; c < 4; ++c) {
            bf16x8 bS = *(const bf16x8*)(bsp + (size_t)c * 16 * cHID + k0);
            bf16x8 bD = *(const bf16x8*)(bdp + (size_t)c * 16 * cHID + k0);
            accS[0][c] = __builtin_amdgcn_mfma_f32_16x16x32_bf16(a0, bS, accS[0][c], 0, 0, 0);
            accS[1][c] = __builtin_amdgcn_mfma_f32_16x16x32_bf16(a1, bS, accS[1][c], 0, 0, 0);
            accD[0][c] = __builtin_amdgcn_mfma_f32_16x16x32_bf16(a0, bD, accD[0][c], 0, 0, 0);
            accD[1][c] = __builtin_amdgcn_mfma_f32_16x16x32_bf16(a1, bD, accD[1][c], 0, 0, 0);
        }
    }
#pragma unroll
    for (int r = 0; r < 2; ++r)
#pragma unroll
        for (int c = 0; c < 4; ++c) {
            int col = n0 + c * 16 + rc;
            float vbs = bs[col], vbd = bd[col];
#pragma unroll
            for (int i = 0; i < 4; ++i) {
                size_t o = (size_t)(m0 + r * 16 + kg * 4 + i) * cHID + col;
                fsb[o] = (__bf16)(accS[r][c][i] + vbs);
                fdb[o] = (__bf16)(accD[r][c][i] + vbd);
            }
        }
}

// ---- CSR build by dst: chunked stable counting sort (deterministic) ----
__global__ __launch_bounds__(256) void k_csr(
    const int* __restrict__ dst, int* __restrict__ csr,
    int* __restrict__ off, int* __restrict__ deg)
{
    __shared__ int dstl[cEPG];
    __shared__ int cnt[cCH * 128];     // [chunk][node] (128-padded rows)
    __shared__ int offl[cNPG];
    __shared__ int tot[128];
    int g = blockIdx.x, tid = threadIdx.x;
    int nb = g * cNPG, eb = g * cEPG;

    for (int i = tid; i < cEPG; i += 256) dstl[i] = dst[eb + i] - nb;
    for (int i = tid; i < cCH * 128; i += 256) cnt[i] = 0;
    __syncthreads();

    for (int i = tid; i < cEPG; i += 256)
        atomicAdd(&cnt[(i / cCHS) * 128 + dstl[i]], 1);
    __syncthreads();

    int mytot = 0;
    if (tid < cNPG) {
        int run = 0;
        for (int c = 0; c < cCH; ++c) {
            int t = cnt[c * 128 + tid];
            cnt[c * 128 + tid] = run;
            run += t;
        }
        mytot = run;
    }
    if (tid < 128) tot[tid] = (tid < cNPG) ? mytot : 0;
    __syncthreads();
    for (int ofs = 1; ofs < 128; ofs <<= 1) {
        int t = 0;
        if (tid < 128 && tid >= ofs) t = tot[tid - ofs];
        __syncthreads();
        if (tid < 128) tot[tid] += t;
        __syncthreads();
    }
    if (tid < cNPG) {
        int excl = tot[tid] - mytot;
        offl[tid] = excl;
        off[nb + tid] = eb + excl;
        deg[nb + tid] = mytot;
    }
    __syncthreads();

    if (tid < cCH) {
        for (int j = 0; j < cCHS; ++j) {
            int i = tid * cCHS + j;
            int n = dstl[i];
            int k = cnt[tid * 128 + n]++;
            csr[eb + offl[n] + k] = eb + i;
        }
    }
}

// ---- fused edge stage: single-pass softmax (no max; scores bounded) ----
__global__ __launch_bounds__(256) void k_edge2(
    const __bf16* __restrict__ fsb, const __bf16* __restrict__ fdb,
    const __bf16* __restrict__ resb, const float* __restrict__ avec,
    const int* __restrict__ csr, const int* __restrict__ off,
    const int* __restrict__ deg, const int* __restrict__ src,
    float* __restrict__ hpre, float* __restrict__ attn_out,
    float* __restrict__ spill, float* __restrict__ bnz)
{
    __shared__ int   sidx[4][64];
    __shared__ float exbuf[4][64];
    int tid = threadIdx.x, lane = tid & 63, w = tid >> 6;
    if (blockIdx.x == 0) {                      // zero BN accumulators (512 floats)
        bnz[tid] = 0.f;
        bnz[tid + 256] = 0.f;
    }
    int n = blockIdx.x * 4 + w;
    int dg = deg[n], base = off[n];

    // prefetch src indices (lane-parallel; breaks dependent gather chain)
    for (int i = lane; i < dg && i < 64; i += 64) sidx[w][i] = src[csr[base + i]];

    float4 a4  = *(const float4*)(avec + lane * 4);
    float4 fd4 = cvt4(*(const bf16x4*)(fdb + (size_t)n * cHID + lane * 4));

    // single pass: score -> exp -> den
    float den = 0.f;
    for (int i = 0; i < dg; ++i) {
        int s = (i < 64) ? sidx[w][i] : src[csr[base + i]];
        float4 f4 = cvt4(*(const bf16x4*)(fsb + (size_t)s * cHID + lane * 4));
        float v0 = f4.x + fd4.x, v1 = f4.y + fd4.y;
        float v2 = f4.z + fd4.z, v3 = f4.w + fd4.w;
        v0 = v0 > 0.f ? v0 : cSLOPE * v0;
        v1 = v1 > 0.f ? v1 : cSLOPE * v1;
        v2 = v2 > 0.f ? v2 : cSLOPE * v2;
        v3 = v3 > 0.f ? v3 : cSLOPE * v3;
        float part = v0 * a4.x + v1 * a4.y + v2 * a4.z + v3 * a4.w;
#pragma unroll
        for (int o = 32; o; o >>= 1) part += __shfl_xor(part, o);
        float ex = __expf(part);
        den += ex;
        if (i < 64) { if (lane == 0) exbuf[w][i] = ex; }
        else        { if (lane == 0) spill[csr[base + i]] = ex; }
    }
    float inv = (dg > 0) ? 1.f / den : 0.f;

    // attn output
    for (int i = lane; i < dg; i += 64) {
        int e = csr[base + i];
        float ex = (i < 64) ? exbuf[w][i] : spill[e];
        attn_out[(size_t)e * 4] = ex * inv;
    }

    // weighted gather + bf16 residual
    float4 acc = {0.f, 0.f, 0.f, 0.f};
    for (int i = 0; i < dg; ++i) {
        int s = (i < 64) ? sidx[w][i] : src[csr[base + i]];
        float al = ((i < 64) ? exbuf[w][i] : spill[csr[base + i]]) * inv;
        float4 f4 = cvt4(*(const bf16x4*)(fsb + (size_t)s * cHID + lane * 4));
        acc.x += al * f4.x; acc.y += al * f4.y;
        acc.z += al * f4.z; acc.w += al * f4.w;
    }
    float4 r4 = cvt4(*(const bf16x4*)(resb + (size_t)n * cHID + lane * 4));
    float4 o4 = {acc.x + r4.x, acc.y + r4.y, acc.z + r4.z, acc.w + r4.w};
    *(float4*)(hpre + (size_t)n * cHID + lane * 4) = o4;
}

// ---- BN stats: grid (200,2); also zeroes this layer's featcat slice ----
__global__ __launch_bounds__(256) void k_bn_stats(
    const float* __restrict__ hpre, float* __restrict__ gsum, float* __restrict__ gssq,
    float* __restrict__ featcat_l)
{
    int j = threadIdx.x, g = blockIdx.x, q = blockIdx.y;
    if (q == 0) featcat_l[(size_t)g * (4 * cHID) + j] = 0.f;
    int rb = g * cNPG + q * 50;
    float s = 0.f, qq = 0.f;
    for (int r = 0; r < 50; ++r) {
        float v = hpre[(size_t)(rb + r) * cHID + j];
        s += v; qq += v * v;
    }
    atomicAdd(&gsum[j], s);
    atomicAdd(&gssq[j], qq);
}

// ---- BN apply + ReLU + graph-mean (atomic): grid (200,4); bf16 h only ----
__global__ __launch_bounds__(256) void k_bn_apply(
    const float* __restrict__ hpre,
    const float* __restrict__ gsum, const float* __restrict__ gssq,
    const float* __restrict__ gamma, const float* __restrict__ beta,
    __bf16* __restrict__ hb, float* __restrict__ featcat_l)
{
    int j = threadIdx.x, g = blockIdx.x, q = blockIdx.y;
    float mu  = gsum[j] * (1.f / cN);
    float var = gssq[j] * (1.f / cN) - mu * mu;
    float sc  = gamma[j] * rsqrtf(var + cEPS);
    float sh  = beta[j] - mu * sc;
    float fsum = 0.f;
    int r0 = g * cNPG + q * 25;
    for (int r = 0; r < 25; ++r) {
        size_t i = (size_t)(r0 + r) * cHID + j;
        float v = hpre[i] * sc + sh;
        v = v > 0.f ? v : 0.f;
        hb[i] = (__bf16)v;
        fsum += v;
    }
    atomicAdd(&featcat_l[(size_t)g * (4 * cHID) + j], fsum * (1.f / cNPG));
}

// ---- head: feat2 = featcat @ fc1_W + fc1_b ----
__global__ __launch_bounds__(256) void k_fc1(
    const float* __restrict__ featcat, const float* __restrict__ W,
    const float* __restrict__ b, float* __restrict__ out)
{
    __shared__ float row[4 * cHID];
    int g = blockIdx.x, j = threadIdx.x;
    for (int i = j; i < 4 * cHID; i += 256) row[i] = featcat[(size_t)g * (4 * cHID) + i];
    __syncthreads();
    float acc = b[j];
    for (int k = 0; k < 4 * cHID; ++k) acc += row[k] * W[(size_t)k * cHID + j];
    out[(size_t)g * cHID + j] = acc;
}

// ---- head BN (over 200 rows) + ReLU, in place ----
__global__ __launch_bounds__(256) void k_fc_bn(
    float* __restrict__ f2, const float* __restrict__ gamma, const float* __restrict__ beta)
{
    int j = threadIdx.x;
    float s = 0.f, q = 0.f;
    for (int r = 0; r < cG; ++r) { float v = f2[(size_t)r * cHID + j]; s += v; q += v * v; }
    float mu  = s * (1.f / cG);
    float var = q * (1.f / cG) - mu * mu;
    float sc  = gamma[j] * rsqrtf(var + cEPS);
    float sh  = beta[j] - mu * sc;
    for (int r = 0; r < cG; ++r) {
        float v = f2[(size_t)r * cHID + j] * sc + sh;
        f2[(size_t)r * cHID + j] = v > 0.f ? v : 0.f;
    }
}

// ---- head: out[r*5+o] = feat2[r] . fc2_W[:,o] + fc2_b[o] ----
__global__ __launch_bounds__(256) void k_fc2(
    const float* __restrict__ f2, const float* __restrict__ W,
    const float* __restrict__ b, float* __restrict__ out)
{
    int t = blockIdx.x * 256 + threadIdx.x;
    if (t >= cG * 5) return;
    int r = t / 5, o = t % 5;
    float acc = b[o];
    for (int k = 0; k < cHID; ++k) acc += f2[(size_t)r * cHID + k] * W[k * 5 + o];
    out[t] = acc;
}

extern "C" void kernel_launch(void* const* d_in, const int* in_sizes, int n_in,
                              void* d_out, int out_size, void* d_ws, size_t ws_size,
                              hipStream_t stream)
{
    (void)in_sizes; (void)n_in; (void)out_size; (void)ws_size;
    const float* x     = (const float*)d_in[0];
    const float* Ws0   = (const float*)d_in[1];
    const float* bs0   = (const float*)d_in[2];
    const float* Wd0   = (const float*)d_in[3];
    const float* bd0   = (const float*)d_in[4];
    const float* a0    = (const float*)d_in[5];
    const float* Wres0 = (const float*)d_in[6];
    const float* g0    = (const float*)d_in[7];
    const float* be0   = (const float*)d_in[8];
    const float* Ws_r  = (const float*)d_in[9];
    const float* bs_r  = (const float*)d_in[10];
    const float* Wd_r  = (const float*)d_in[11];
    const float* bd_r  = (const float*)d_in[12];
    const float* a_r   = (const float*)d_in[13];
    const float* g_r   = (const float*)d_in[14];
    const float* be_r  = (const float*)d_in[15];
    const float* fc1_W = (const float*)d_in[16];
    const float* fc1_b = (const float*)d_in[17];
    const float* gfc   = (const float*)d_in[18];
    const float* bfc   = (const float*)d_in[19];
    const float* fc2_W = (const float*)d_in[20];
    const float* fc2_b = (const float*)d_in[21];
    const int*   src   = (const int*)d_in[22];
    const int*   dst   = (const int*)d_in[23];
    float* out = (float*)d_out;

    char* p = (char*)d_ws;
    float* hpre    = (float*)p; p += (size_t)cN * cHID * 4;
    float* featcat = (float*)p; p += (size_t)cG * 4 * cHID * 4;
    float* feat2   = (float*)p; p += (size_t)cG * cHID * 4;
    float* gsum    = (float*)p; p += cHID * 4;
    float* gssq    = (float*)p; p += cHID * 4;
    float* spill   = (float*)p; p += (size_t)cE * 4;
    int*   csr     = (int*)p;   p += (size_t)cE * 4;
    int*   offv    = (int*)p;   p += (size_t)cN * 4;
    int*   degv    = (int*)p;   p += (size_t)cN * 4;
    __bf16* hb     = (__bf16*)p; p += (size_t)cN * cHID * 2;
    __bf16* resb0  = (__bf16*)p; p += (size_t)cN * cHID * 2;
    __bf16* fsb    = (__bf16*)p; p += (size_t)cN * cHID * 2;
    __bf16* fdb    = (__bf16*)p; p += (size_t)cN * cHID * 2;
    __bf16* WT     = (__bf16*)p; p += (size_t)6 * cHID * cHID * 2;

    // one-time setup: weight convert/transpose + CSR by dst
    k_wcvt<<<dim3(cHID, 6), 256, 0, stream>>>(Ws_r, Wd_r, WT);
    k_csr<<<cG, 256, 0, stream>>>(dst, csr, offv, degv);

    // layer 0 projections (f32 math, bf16 emit)
    k_in_gemm<<<cN / 8, 256, 0, stream>>>(x, Ws0, bs0, Wd0, bd0, Wres0, fsb, fdb, resb0);

    for (int l = 0; l < 4; ++l) {
        if (l > 0) {
            k_gemm_mfma<<<dim3((cN / 32 + 3) / 4, 4), 256, 0, stream>>>(
                hb,
                WT + (size_t)(2 * (l - 1)) * cHID * cHID,
                WT + (size_t)(2 * (l - 1) + 1) * cHID * cHID,
                bs_r + (size_t)(l - 1) * cHID, bd_r + (size_t)(l - 1) * cHID,
                fsb, fdb);
        }
        const float* ap = (l == 0) ? a0 : a_r + (size_t)(l - 1) * cHID;
        const __bf16* rb = (l == 0) ? resb0 : hb;
        k_edge2<<<cN / 4, 256, 0, stream>>>(fsb, fdb, rb, ap, csr, offv, degv, src,
                                            hpre, out + 1000 + l, spill, gsum);
        float* fcl = featcat + (size_t)l * cHID;
        k_bn_stats<<<dim3(cG, 2), 256, 0, stream>>>(hpre, gsum, gssq, fcl);
        const float* gm = (l == 0) ? g0  : g_r  + (size_t)(l - 1) * cHID;
        const float* bt = (l == 0) ? be0 : be_r + (size_t)(l - 1) * cHID;
        k_bn_apply<<<dim3(cG, 4), 256, 0, stream>>>(hpre, gsum, gssq, gm, bt, hb, fcl);
    }

    k_fc1<<<cG, 256, 0, stream>>>(featcat, fc1_W, fc1_b, feat2);
    k_fc_bn<<<1, 256, 0, stream>>>(feat2, gfc, bfc);
    k_fc2<<<4, 256, 0, stream>>>(feat2, fc2_W, fc2_b, out);
}